// Round 7
// baseline (730.654 us; speedup 1.0000x reference)
//
#include <hip/hip_runtime.h>
#include <hip/hip_bf16.h>

#define BB 32
#define LL 128
#define DD 400
#define KK 40
#define SDN 52   // d-slots padded (400/8 -> 52, zeros above 400)
#define SEN 52   // e-slots (416/8)
#define EP 512   // e padded for k_T M-tiles
#define KHALF 20

typedef __attribute__((ext_vector_type(8))) short bfrag;   // 8 bf16 (A/B frag 16x16x32)
typedef __attribute__((ext_vector_type(4))) float cfrag;   // 4 fp32 (C/D frag 16x16x32)

static __device__ __forceinline__ short f2bf(float f) {
    union { float f; unsigned u; } v; v.f = f;
    unsigned r = (v.u + 0x7FFF + ((v.u >> 16) & 1)) >> 16;
    return (short)r;
}
static __device__ __forceinline__ unsigned pack2(float a, float b) {
    return (unsigned)(unsigned short)f2bf(a) | ((unsigned)(unsigned short)f2bf(b) << 16);
}

// ---------------------------------------------------------------------------
// Hs[b][sd(52)][h][8] (d-pad zero), Cs[b][se(52)][c][8] (e-pad zero)
// ---------------------------------------------------------------------------
__global__ __launch_bounds__(256) void p_hc(
    const float* __restrict__ H, const float* __restrict__ C,
    short* __restrict__ Hs, short* __restrict__ Cs)
{
    int id = blockIdx.x * 256 + threadIdx.x;
    const int NH = BB*SDN*LL;
    if (id < NH) {
        int b = id / (SDN*LL); int r = id % (SDN*LL);
        int sd = r / LL; int h = r % LL;
        bfrag v;
#pragma unroll
        for (int j = 0; j < 8; ++j) {
            int d = sd*8 + j;
            v[j] = (d < DD) ? f2bf(H[((size_t)(b*LL + h))*DD + d]) : (short)0;
        }
        *(bfrag*)(Hs + (size_t)id*8) = v;
    } else if (id < 2*NH) {
        id -= NH;
        int b = id / (SEN*LL); int r = id % (SEN*LL);
        int se = r / LL; int c = r % LL;
        bfrag v;
#pragma unroll
        for (int j = 0; j < 8; ++j) {
            int e = se*8 + j;
            v[j] = (e < DD) ? f2bf(C[((size_t)(b*LL + c))*DD + e]) : (short)0;
        }
        *(bfrag*)(Cs + (size_t)id*8) = v;
    }
}

// Us[k][sd(52)][e(512)][8] = bf16(U[k][sd*8+j][e]); zero outside d<400, e<416
__global__ __launch_bounds__(256) void p_u(
    const float* __restrict__ U, short* __restrict__ Us)
{
    int id = blockIdx.x * 256 + threadIdx.x;   // < 40*52*512
    if (id >= KK*SDN*EP) return;
    int k = id / (SDN*EP); int r = id % (SDN*EP);
    int sd = r / EP; int e = r % EP;
    bfrag v;
#pragma unroll
    for (int j = 0; j < 8; ++j) {
        int d = sd*8 + j;
        v[j] = (d < DD && e < DD) ? f2bf(U[((size_t)k*DD + d)*DD + e]) : (short)0;
    }
    *(bfrag*)(Us + (size_t)id*8) = v;
}

// ---------------------------------------------------------------------------
// SD[b,k,h] = W_d[k].h[b,h]   SE[b,k,c] = W_e[k].c[b,c]   (fp32 exact)
// ---------------------------------------------------------------------------
__global__ __launch_bounds__(256) void k_sdse(
    const float* __restrict__ H, const float* __restrict__ C,
    const float* __restrict__ Wd, const float* __restrict__ We,
    float* __restrict__ SD, float* __restrict__ SE)
{
    const int k = blockIdx.x % KK;
    const int b = blockIdx.x / KK;
    const int t = threadIdx.x;
    __shared__ float wd[DD], we[DD];
    for (int f = t; f < DD; f += 256) { wd[f] = Wd[k*DD + f]; we[f] = We[k*DD + f]; }
    __syncthreads();
    const int row = t & 127;
    const float* src = (t < 128) ? (H + (size_t)(b*LL + row)*DD)
                                 : (C + (size_t)(b*LL + row)*DD);
    const float* w = (t < 128) ? wd : we;
    float s = 0.f;
    for (int d = 0; d < DD; d += 4) {
        float4 v = *(const float4*)(src + d);
        s = fmaf(v.x, w[d+0], s); s = fmaf(v.y, w[d+1], s);
        s = fmaf(v.z, w[d+2], s); s = fmaf(v.w, w[d+3], s);
    }
    if (t < 128) SD[(b*KK + k)*LL + row] = s;
    else         SE[(b*KK + k)*LL + row] = s;
}

// ---------------------------------------------------------------------------
// k_T: T[kk,b,e,h] = sum_d Ut[kk][e][d] * H[b][h][d]  (unchanged from R6)
// ---------------------------------------------------------------------------
__global__ __launch_bounds__(256, 2) void k_T(
    const short* __restrict__ Us, const short* __restrict__ Hs,
    short* __restrict__ Tb, int k0)
{
    const int et = blockIdx.x;       // 0..3
    const int b  = blockIdx.y;       // 0..31
    const int kz = blockIdx.z;       // 0..KHALF-1
    const int kk = k0 + kz;
    const int t = threadIdx.x;
    const int w = t >> 6, l = t & 63;
    const int wr = w >> 1, wc = w & 1;
    const int l15 = l & 15, l4 = l >> 4;

    const int m0 = et*128 + wr*64;   // e base
    const int n0 = wc*64;            // h base

    const bfrag* A = (const bfrag*)(Us + (size_t)kk*SDN*EP*8);
    const bfrag* Bv = (const bfrag*)(Hs + (size_t)b*SDN*LL*8);

    cfrag acc[4][4];
#pragma unroll
    for (int i = 0; i < 4; ++i)
#pragma unroll
        for (int j = 0; j < 4; ++j)
#pragma unroll
            for (int r = 0; r < 4; ++r) acc[i][j][r] = 0.f;

    bfrag af[4], bf[4];
#pragma unroll
    for (int i = 0; i < 4; ++i) {
        af[i] = A[l4*EP + m0 + i*16 + l15];
        bf[i] = Bv[l4*LL + n0 + i*16 + l15];
    }
    for (int sdc = 0; sdc < 13; ++sdc) {
        bfrag afn[4], bfn[4];
        if (sdc < 12) {
            const int sdn = (sdc + 1)*4 + l4;
#pragma unroll
            for (int i = 0; i < 4; ++i) {
                afn[i] = A[sdn*EP + m0 + i*16 + l15];
                bfn[i] = Bv[sdn*LL + n0 + i*16 + l15];
            }
        } else {
#pragma unroll
            for (int i = 0; i < 4; ++i) { afn[i] = af[i]; bfn[i] = bf[i]; }
        }
#pragma unroll
        for (int mf = 0; mf < 4; ++mf)
#pragma unroll
            for (int nf = 0; nf < 4; ++nf)
                acc[mf][nf] = __builtin_amdgcn_mfma_f32_16x16x32_bf16(
                    af[mf], bf[nf], acc[mf][nf], 0, 0, 0);
#pragma unroll
        for (int i = 0; i < 4; ++i) { af[i] = afn[i]; bf[i] = bfn[i]; }
    }

    short* To = Tb + (size_t)(kz*BB + b)*SEN*LL*8;
#pragma unroll
    for (int mf = 0; mf < 4; ++mf) {
        const int e0 = m0 + mf*16 + l4*4;
        if (e0 < 416) {
            const int se = e0 >> 3, e7 = e0 & 7;
#pragma unroll
            for (int nf = 0; nf < 4; ++nf) {
                const int h = n0 + nf*16 + l15;
                uint2 pv;
                pv.x = pack2(acc[mf][nf][0], acc[mf][nf][1]);
                pv.y = pack2(acc[mf][nf][2], acc[mf][nf][3]);
                *(uint2*)(To + (size_t)(se*LL + h)*8 + e7) = pv;
            }
        }
    }
}

// ---------------------------------------------------------------------------
// k_A: per block = (b, 64x64 hc-tile): loop kz over this half's 20 tags,
// GEMM the tile (A=Tb frags, B=Cs frags, both L2-hot, prefetch depth 1),
// fused energy/exp epilogue accumulated in REGISTERS across k.
// Output: plain stores to A2[half] (no atomics). Rare gold-arc atomics to tgt.
// ---------------------------------------------------------------------------
__global__ __launch_bounds__(256) void k_A(
    const short* __restrict__ Tb, const short* __restrict__ Cs,
    const float* __restrict__ SD, const float* __restrict__ SE,
    const float* __restrict__ bvec, const float* __restrict__ mask,
    const int* __restrict__ heads, const int* __restrict__ tags,
    float* __restrict__ A2, float* __restrict__ tgt, int k0, int half)
{
    const int tile = blockIdx.x;        // 0..3
    const int b = blockIdx.y;
    const int ht = tile >> 1, ct = tile & 1;
    const int t = threadIdx.x;
    const int w = t >> 6, l = t & 63;
    const int wr = w >> 1, wc = w & 1;
    const int l15 = l & 15, l4 = l >> 4;
    const int h0 = ht*64 + wr*32;
    const int c0 = ct*64 + wc*32;

    const bfrag* Bv = (const bfrag*)(Cs + (size_t)b*SEN*LL*8);

    // k-invariant epilogue data
    float mcv[2]; int hdv[2], tgv[2];
#pragma unroll
    for (int nf = 0; nf < 2; ++nf) {
        const int c = c0 + nf*16 + l15;
        mcv[nf] = mask[b*LL + c];
        hdv[nf] = heads[b*LL + c];
        tgv[nf] = tags[b*LL + c];
    }
    float mhv[2][4];
#pragma unroll
    for (int mf = 0; mf < 2; ++mf)
#pragma unroll
        for (int r = 0; r < 4; ++r)
            mhv[mf][r] = mask[b*LL + h0 + mf*16 + l4*4 + r];

    float aacc[2][2][4];
#pragma unroll
    for (int i = 0; i < 2; ++i)
#pragma unroll
        for (int j = 0; j < 2; ++j)
#pragma unroll
            for (int r = 0; r < 4; ++r) aacc[i][j][r] = 0.f;
    float tacc = 0.f; bool hit = false;

    for (int kz = 0; kz < KHALF; ++kz) {
        const int kk = k0 + kz;
        const bfrag* Av = (const bfrag*)(Tb + (size_t)(kz*BB + b)*SEN*LL*8);

        cfrag S[2][2];
#pragma unroll
        for (int i = 0; i < 2; ++i)
#pragma unroll
            for (int j = 0; j < 2; ++j)
#pragma unroll
                for (int r = 0; r < 4; ++r) S[i][j][r] = 0.f;

        bfrag af[2], bf[2];
#pragma unroll
        for (int i = 0; i < 2; ++i) {
            af[i] = Av[l4*LL + h0 + i*16 + l15];
            bf[i] = Bv[l4*LL + c0 + i*16 + l15];
        }
        for (int esc = 0; esc < 13; ++esc) {
            bfrag afn[2], bfn[2];
            if (esc < 12) {
                const int sen = (esc + 1)*4 + l4;
#pragma unroll
                for (int i = 0; i < 2; ++i) {
                    afn[i] = Av[sen*LL + h0 + i*16 + l15];
                    bfn[i] = Bv[sen*LL + c0 + i*16 + l15];
                }
            } else {
#pragma unroll
                for (int i = 0; i < 2; ++i) { afn[i] = af[i]; bfn[i] = bf[i]; }
            }
#pragma unroll
            for (int mf = 0; mf < 2; ++mf)
#pragma unroll
                for (int nf = 0; nf < 2; ++nf)
                    S[mf][nf] = __builtin_amdgcn_mfma_f32_16x16x32_bf16(
                        af[mf], bf[nf], S[mf][nf], 0, 0, 0);
#pragma unroll
            for (int i = 0; i < 2; ++i) { af[i] = afn[i]; bf[i] = bfn[i]; }
        }

        // epilogue for this k
        const float bk = bvec[kk];
        const float* SDb = SD + ((size_t)b*KK + kk)*LL;
        const float* SEb = SE + ((size_t)b*KK + kk)*LL;
#pragma unroll
        for (int nf = 0; nf < 2; ++nf) {
            const int c = c0 + nf*16 + l15;
            const float sev = SEb[c];
#pragma unroll
            for (int mf = 0; mf < 2; ++mf) {
                const int hb = h0 + mf*16 + l4*4;
#pragma unroll
                for (int r = 0; r < 4; ++r) {
                    const int h = hb + r;
                    const bool live = (h != c) && (mhv[mf][r] != 0.f) && (mcv[nf] != 0.f);
                    if (live) {
                        const float eng = S[mf][nf][r] + SDb[h] + sev + bk;
                        aacc[mf][nf][r] += __expf(eng);
                        if (c >= 1 && tgv[nf] == kk && hdv[nf] == h) { tacc += eng; hit = true; }
                    }
                }
            }
        }
    }

    // write tile (unique ownership, no atomics)
    float* Ab = A2 + ((size_t)(half*BB + b))*LL*LL;
#pragma unroll
    for (int mf = 0; mf < 2; ++mf) {
        const int hb = h0 + mf*16 + l4*4;
#pragma unroll
        for (int r = 0; r < 4; ++r)
#pragma unroll
            for (int nf = 0; nf < 2; ++nf)
                Ab[(hb + r)*LL + c0 + nf*16 + l15] = aacc[mf][nf][r];
    }
    if (hit) atomicAdd(&tgt[b], tacc);
}

// ---------------------------------------------------------------------------
// Register-resident LU logdet; float4 L/U publish (conflict-free broadcast),
// double-buffered Lb/Ub -> ONE barrier per pivot step. Sums the two A2
// slices during the As load (k_asum fused away).
// ---------------------------------------------------------------------------
__global__ __launch_bounds__(256) void k_logdet(
    const float* __restrict__ A2, const int* __restrict__ lengths,
    const float* __restrict__ tgt, float* __restrict__ out)
{
    const int b = blockIdx.x;
    const int t = threadIdx.x;
    const int rg = t >> 4, cg = t & 15;

    __shared__ float As[LL*LL];
    __shared__ float Dg[128];
    __shared__ float Lb[2][128];
    __shared__ float Ub[2][128];
    __shared__ float Pv[128];
    __shared__ float red[256];

    const float4* A4 = (const float4*)A2;
    for (int f4 = t; f4 < 4096; f4 += 256) {
        float4 x = A4[(size_t)b*4096 + f4];
        float4 y = A4[(size_t)(BB + b)*4096 + f4];
        x.x += y.x; x.y += y.y; x.z += y.z; x.w += y.w;
        ((float4*)As)[f4] = x;
    }
    __syncthreads();

    if (t < 128) {
        float s = 0.f;
        for (int hr = 0; hr < LL; ++hr) s += As[hr*LL + t];
        Dg[t] = s * (1.0f + 1e-4f) + 1e-6f;
    }
    __syncthreads();

    const int n1 = lengths[b] - 1;
    float m[8][8];
#pragma unroll
    for (int r = 0; r < 8; ++r) {
        const int i = 8*rg + r;
#pragma unroll
        for (int c = 0; c < 8; ++c) {
            const int j = 8*cg + c;
            float v;
            if (i < n1 && j < n1)
                v = ((i == j) ? Dg[i+1] : 0.f) - As[(i+1)*LL + (j+1)];
            else
                v = (i == j) ? 1.f : 0.f;
            m[r][c] = v;
        }
    }
    // publish pivot 0 (column/row group 0, element 0)
    if (cg == 0) {
        *(float4*)&Lb[0][8*rg]     = make_float4(m[0][0], m[1][0], m[2][0], m[3][0]);
        *(float4*)&Lb[0][8*rg + 4] = make_float4(m[4][0], m[5][0], m[6][0], m[7][0]);
    }
    if (rg == 0) {
        *(float4*)&Ub[0][8*cg]     = make_float4(m[0][0], m[0][1], m[0][2], m[0][3]);
        *(float4*)&Ub[0][8*cg + 4] = make_float4(m[0][4], m[0][5], m[0][6], m[0][7]);
    }
    __syncthreads();

    for (int j = 0; j < 127; ++j) {
        const int cur = j & 1, nxt = cur ^ 1;
        const float piv = Lb[cur][j];
        if (t == j) Pv[j] = piv;
        const float rp = 1.0f / piv;
        const float4 l0 = *(const float4*)&Lb[cur][8*rg];
        const float4 l1 = *(const float4*)&Lb[cur][8*rg + 4];
        const float4 u0 = *(const float4*)&Ub[cur][8*cg];
        const float4 u1 = *(const float4*)&Ub[cur][8*cg + 4];
        const float lr[8] = { l0.x*rp, l0.y*rp, l0.z*rp, l0.w*rp,
                              l1.x*rp, l1.y*rp, l1.z*rp, l1.w*rp };
        const float ur[8] = { u0.x, u0.y, u0.z, u0.w, u1.x, u1.y, u1.z, u1.w };
#pragma unroll
        for (int r = 0; r < 8; ++r)
#pragma unroll
            for (int c = 0; c < 8; ++c)
                m[r][c] = fmaf(-lr[r], ur[c], m[r][c]);

        if (j < 126) {
            const int jn = j + 1, jg = jn >> 3, jl = jn & 7;
            if (cg == jg) {
#pragma unroll
                for (int c = 0; c < 8; ++c) {
                    if (c == jl) {
                        *(float4*)&Lb[nxt][8*rg]     = make_float4(m[0][c], m[1][c], m[2][c], m[3][c]);
                        *(float4*)&Lb[nxt][8*rg + 4] = make_float4(m[4][c], m[5][c], m[6][c], m[7][c]);
                    }
                }
            }
            if (rg == jg) {
#pragma unroll
                for (int r = 0; r < 8; ++r) {
                    if (r == jl) {
                        *(float4*)&Ub[nxt][8*cg]     = make_float4(m[r][0], m[r][1], m[r][2], m[r][3]);
                        *(float4*)&Ub[nxt][8*cg + 4] = make_float4(m[r][4], m[r][5], m[r][6], m[r][7]);
                    }
                }
            }
        }
        __syncthreads();
    }

    float lsum = 0.f;
    if (t < 127) lsum = logf(Pv[t]);
    red[t] = lsum;
    __syncthreads();
    for (int off = 128; off >= 1; off >>= 1) {
        if (t < off) red[t] += red[t + off];
        __syncthreads();
    }
    if (t == 0) out[b] = red[0] - tgt[b];
}

// ---------------------------------------------------------------------------
extern "C" void kernel_launch(void* const* d_in, const int* in_sizes, int n_in,
                              void* d_out, int out_size, void* d_ws, size_t ws_size,
                              hipStream_t stream) {
    const float* H    = (const float*)d_in[0];
    const float* C    = (const float*)d_in[1];
    const float* Wd   = (const float*)d_in[2];
    const float* We   = (const float*)d_in[3];
    const float* U    = (const float*)d_in[4];
    const float* bv   = (const float*)d_in[5];
    const float* mask = (const float*)d_in[6];
    const int* heads  = (const int*)d_in[7];
    const int* tags   = (const int*)d_in[8];
    const int* lens   = (const int*)d_in[9];
    float* out = (float*)d_out;

    // workspace layout (~97 MB)
    char* p = (char*)d_ws;
    float* tgt = (float*)p;                 p += 128*4;
    float* A2  = (float*)p;                 p += (size_t)2*BB*LL*LL*4;      // 4.19 MB
    float* SDp = (float*)p;                 p += (size_t)BB*KK*LL*4;        // 0.66 MB
    float* SEp = (float*)p;                 p += (size_t)BB*KK*LL*4;        // 0.66 MB
    short* Hsp = (short*)p;                 p += (size_t)BB*SDN*LL*8*2;     // 3.41 MB
    short* Csp = (short*)p;                 p += (size_t)BB*SEN*LL*8*2;     // 3.41 MB
    short* Usp = (short*)p;                 p += (size_t)KK*SDN*EP*8*2;     // 17.04 MB
    short* Tbp = (short*)p;                 p += (size_t)KHALF*BB*SEN*LL*8*2; // 68.16 MB

    hipMemsetAsync(tgt, 0, 128*4, stream);

    p_hc  <<<dim3(1664), 256, 0, stream>>>(H, C, Hsp, Csp);
    p_u   <<<dim3(4160), 256, 0, stream>>>(U, Usp);
    k_sdse<<<dim3(BB*KK), 256, 0, stream>>>(H, C, Wd, We, SDp, SEp);

    for (int half = 0; half < 2; ++half) {
        const int k0 = half * KHALF;
        k_T<<<dim3(4, BB, KHALF), 256, 0, stream>>>(Usp, Hsp, Tbp, k0);
        k_A<<<dim3(4, BB), 256, 0, stream>>>(Tbp, Csp, SDp, SEp, bv, mask,
                                             heads, tags, A2, tgt, k0, half);
    }

    k_logdet<<<dim3(BB), 256, 0, stream>>>(A2, lens, tgt, out);
}

// Round 8
// 506.062 us; speedup vs baseline: 1.4438x; 1.4438x over previous
//
#include <hip/hip_runtime.h>
#include <hip/hip_bf16.h>

#define BB 32
#define LL 128
#define DD 400
#define KK 40
#define SDN 52   // d-slots padded (400/8 -> 52, zeros above 400)
#define SEN 52   // e-slots (416/8)
#define EP 512   // e padded for k_T M-tiles
#define KHALF 20
#define NG 5     // k-groups per half
#define GSZ 4    // k's per group
#define NSL (2*NG)  // total A slices

typedef __attribute__((ext_vector_type(8))) short bfrag;   // 8 bf16 (A/B frag 16x16x32)
typedef __attribute__((ext_vector_type(4))) float cfrag;   // 4 fp32 (C/D frag 16x16x32)

static __device__ __forceinline__ short f2bf(float f) {
    union { float f; unsigned u; } v; v.f = f;
    unsigned r = (v.u + 0x7FFF + ((v.u >> 16) & 1)) >> 16;
    return (short)r;
}
static __device__ __forceinline__ unsigned pack2(float a, float b) {
    return (unsigned)(unsigned short)f2bf(a) | ((unsigned)(unsigned short)f2bf(b) << 16);
}

// ---------------------------------------------------------------------------
// Hs[b][sd(52)][h][8] (d-pad zero), Cs[b][se(52)][c][8] (e-pad zero)
// ---------------------------------------------------------------------------
__global__ __launch_bounds__(256) void p_hc(
    const float* __restrict__ H, const float* __restrict__ C,
    short* __restrict__ Hs, short* __restrict__ Cs)
{
    int id = blockIdx.x * 256 + threadIdx.x;
    const int NH = BB*SDN*LL;
    if (id < NH) {
        int b = id / (SDN*LL); int r = id % (SDN*LL);
        int sd = r / LL; int h = r % LL;
        bfrag v;
#pragma unroll
        for (int j = 0; j < 8; ++j) {
            int d = sd*8 + j;
            v[j] = (d < DD) ? f2bf(H[((size_t)(b*LL + h))*DD + d]) : (short)0;
        }
        *(bfrag*)(Hs + (size_t)id*8) = v;
    } else if (id < 2*NH) {
        id -= NH;
        int b = id / (SEN*LL); int r = id % (SEN*LL);
        int se = r / LL; int c = r % LL;
        bfrag v;
#pragma unroll
        for (int j = 0; j < 8; ++j) {
            int e = se*8 + j;
            v[j] = (e < DD) ? f2bf(C[((size_t)(b*LL + c))*DD + e]) : (short)0;
        }
        *(bfrag*)(Cs + (size_t)id*8) = v;
    }
}

// Us[k][sd(52)][e(512)][8] = bf16(U[k][sd*8+j][e]); zero outside d<400, e<416
__global__ __launch_bounds__(256) void p_u(
    const float* __restrict__ U, short* __restrict__ Us)
{
    int id = blockIdx.x * 256 + threadIdx.x;   // < 40*52*512
    if (id >= KK*SDN*EP) return;
    int k = id / (SDN*EP); int r = id % (SDN*EP);
    int sd = r / EP; int e = r % EP;
    bfrag v;
#pragma unroll
    for (int j = 0; j < 8; ++j) {
        int d = sd*8 + j;
        v[j] = (d < DD && e < DD) ? f2bf(U[((size_t)k*DD + d)*DD + e]) : (short)0;
    }
    *(bfrag*)(Us + (size_t)id*8) = v;
}

// ---------------------------------------------------------------------------
// SD[b,k,h] = W_d[k].h[b,h]   SE[b,k,c] = W_e[k].c[b,c]   (fp32 exact)
// ---------------------------------------------------------------------------
__global__ __launch_bounds__(256) void k_sdse(
    const float* __restrict__ H, const float* __restrict__ C,
    const float* __restrict__ Wd, const float* __restrict__ We,
    float* __restrict__ SD, float* __restrict__ SE)
{
    const int k = blockIdx.x % KK;
    const int b = blockIdx.x / KK;
    const int t = threadIdx.x;
    __shared__ float wd[DD], we[DD];
    for (int f = t; f < DD; f += 256) { wd[f] = Wd[k*DD + f]; we[f] = We[k*DD + f]; }
    __syncthreads();
    const int row = t & 127;
    const float* src = (t < 128) ? (H + (size_t)(b*LL + row)*DD)
                                 : (C + (size_t)(b*LL + row)*DD);
    const float* w = (t < 128) ? wd : we;
    float s = 0.f;
    for (int d = 0; d < DD; d += 4) {
        float4 v = *(const float4*)(src + d);
        s = fmaf(v.x, w[d+0], s); s = fmaf(v.y, w[d+1], s);
        s = fmaf(v.z, w[d+2], s); s = fmaf(v.w, w[d+3], s);
    }
    if (t < 128) SD[(b*KK + k)*LL + row] = s;
    else         SE[(b*KK + k)*LL + row] = s;
}

// ---------------------------------------------------------------------------
// k_T: T[kk,b,e,h] = sum_d Ut[kk][e][d] * H[b][h][d]  (unchanged)
// ---------------------------------------------------------------------------
__global__ __launch_bounds__(256, 2) void k_T(
    const short* __restrict__ Us, const short* __restrict__ Hs,
    short* __restrict__ Tb, int k0)
{
    const int et = blockIdx.x;       // 0..3
    const int b  = blockIdx.y;       // 0..31
    const int kz = blockIdx.z;       // 0..KHALF-1
    const int kk = k0 + kz;
    const int t = threadIdx.x;
    const int w = t >> 6, l = t & 63;
    const int wr = w >> 1, wc = w & 1;
    const int l15 = l & 15, l4 = l >> 4;

    const int m0 = et*128 + wr*64;   // e base
    const int n0 = wc*64;            // h base

    const bfrag* A = (const bfrag*)(Us + (size_t)kk*SDN*EP*8);
    const bfrag* Bv = (const bfrag*)(Hs + (size_t)b*SDN*LL*8);

    cfrag acc[4][4];
#pragma unroll
    for (int i = 0; i < 4; ++i)
#pragma unroll
        for (int j = 0; j < 4; ++j)
#pragma unroll
            for (int r = 0; r < 4; ++r) acc[i][j][r] = 0.f;

    bfrag af[4], bf[4];
#pragma unroll
    for (int i = 0; i < 4; ++i) {
        af[i] = A[l4*EP + m0 + i*16 + l15];
        bf[i] = Bv[l4*LL + n0 + i*16 + l15];
    }
    for (int sdc = 0; sdc < 13; ++sdc) {
        bfrag afn[4], bfn[4];
        if (sdc < 12) {
            const int sdn = (sdc + 1)*4 + l4;
#pragma unroll
            for (int i = 0; i < 4; ++i) {
                afn[i] = A[sdn*EP + m0 + i*16 + l15];
                bfn[i] = Bv[sdn*LL + n0 + i*16 + l15];
            }
        } else {
#pragma unroll
            for (int i = 0; i < 4; ++i) { afn[i] = af[i]; bfn[i] = bf[i]; }
        }
#pragma unroll
        for (int mf = 0; mf < 4; ++mf)
#pragma unroll
            for (int nf = 0; nf < 4; ++nf)
                acc[mf][nf] = __builtin_amdgcn_mfma_f32_16x16x32_bf16(
                    af[mf], bf[nf], acc[mf][nf], 0, 0, 0);
#pragma unroll
        for (int i = 0; i < 4; ++i) { af[i] = afn[i]; bf[i] = bfn[i]; }
    }

    short* To = Tb + (size_t)(kz*BB + b)*SEN*LL*8;
#pragma unroll
    for (int mf = 0; mf < 4; ++mf) {
        const int e0 = m0 + mf*16 + l4*4;
        if (e0 < 416) {
            const int se = e0 >> 3, e7 = e0 & 7;
#pragma unroll
            for (int nf = 0; nf < 4; ++nf) {
                const int h = n0 + nf*16 + l15;
                uint2 pv;
                pv.x = pack2(acc[mf][nf][0], acc[mf][nf][1]);
                pv.y = pack2(acc[mf][nf][2], acc[mf][nf][3]);
                *(uint2*)(To + (size_t)(se*LL + h)*8 + e7) = pv;
            }
        }
    }
}

// ---------------------------------------------------------------------------
// k_A: block = (hc-tile, b, k-group of 4). GEMM each k's 64x64 tile
// (A=Tb, B=Cs frags from global), fused exp epilogue accumulated in regs
// across the group's 4 k's; plain stores to slice A10[half*NG + kg].
// ---------------------------------------------------------------------------
__global__ __launch_bounds__(256) void k_A(
    const short* __restrict__ Tb, const short* __restrict__ Cs,
    const float* __restrict__ SD, const float* __restrict__ SE,
    const float* __restrict__ bvec, const float* __restrict__ mask,
    const int* __restrict__ heads, const int* __restrict__ tags,
    float* __restrict__ A10, float* __restrict__ tgt, int k0, int sliceBase)
{
    const int tile = blockIdx.x;        // 0..3
    const int b = blockIdx.y;
    const int kg = blockIdx.z;          // 0..NG-1
    const int ht = tile >> 1, ct = tile & 1;
    const int t = threadIdx.x;
    const int w = t >> 6, l = t & 63;
    const int wr = w >> 1, wc = w & 1;
    const int l15 = l & 15, l4 = l >> 4;
    const int h0 = ht*64 + wr*32;
    const int c0 = ct*64 + wc*32;

    const bfrag* Bv = (const bfrag*)(Cs + (size_t)b*SEN*LL*8);

    // k-invariant epilogue data
    float mcv[2]; int hdv[2], tgv[2];
#pragma unroll
    for (int nf = 0; nf < 2; ++nf) {
        const int c = c0 + nf*16 + l15;
        mcv[nf] = mask[b*LL + c];
        hdv[nf] = heads[b*LL + c];
        tgv[nf] = tags[b*LL + c];
    }
    float mhv[2][4];
#pragma unroll
    for (int mf = 0; mf < 2; ++mf)
#pragma unroll
        for (int r = 0; r < 4; ++r)
            mhv[mf][r] = mask[b*LL + h0 + mf*16 + l4*4 + r];

    float aacc[2][2][4];
#pragma unroll
    for (int i = 0; i < 2; ++i)
#pragma unroll
        for (int j = 0; j < 2; ++j)
#pragma unroll
            for (int r = 0; r < 4; ++r) aacc[i][j][r] = 0.f;
    float tacc = 0.f; bool hit = false;

    for (int g = 0; g < GSZ; ++g) {
        const int kz = kg*GSZ + g;
        const int kk = k0 + kz;
        const bfrag* Av = (const bfrag*)(Tb + (size_t)(kz*BB + b)*SEN*LL*8);

        cfrag S[2][2];
#pragma unroll
        for (int i = 0; i < 2; ++i)
#pragma unroll
            for (int j = 0; j < 2; ++j)
#pragma unroll
                for (int r = 0; r < 4; ++r) S[i][j][r] = 0.f;

        bfrag af[2], bf[2];
#pragma unroll
        for (int i = 0; i < 2; ++i) {
            af[i] = Av[l4*LL + h0 + i*16 + l15];
            bf[i] = Bv[l4*LL + c0 + i*16 + l15];
        }
        for (int esc = 0; esc < 13; ++esc) {
            bfrag afn[2], bfn[2];
            if (esc < 12) {
                const int sen = (esc + 1)*4 + l4;
#pragma unroll
                for (int i = 0; i < 2; ++i) {
                    afn[i] = Av[sen*LL + h0 + i*16 + l15];
                    bfn[i] = Bv[sen*LL + c0 + i*16 + l15];
                }
            } else {
#pragma unroll
                for (int i = 0; i < 2; ++i) { afn[i] = af[i]; bfn[i] = bf[i]; }
            }
#pragma unroll
            for (int mf = 0; mf < 2; ++mf)
#pragma unroll
                for (int nf = 0; nf < 2; ++nf)
                    S[mf][nf] = __builtin_amdgcn_mfma_f32_16x16x32_bf16(
                        af[mf], bf[nf], S[mf][nf], 0, 0, 0);
#pragma unroll
            for (int i = 0; i < 2; ++i) { af[i] = afn[i]; bf[i] = bfn[i]; }
        }

        // epilogue for this k
        const float bk = bvec[kk];
        const float* SDb = SD + ((size_t)b*KK + kk)*LL;
        const float* SEb = SE + ((size_t)b*KK + kk)*LL;
#pragma unroll
        for (int nf = 0; nf < 2; ++nf) {
            const int c = c0 + nf*16 + l15;
            const float sev = SEb[c];
#pragma unroll
            for (int mf = 0; mf < 2; ++mf) {
                const int hb = h0 + mf*16 + l4*4;
#pragma unroll
                for (int r = 0; r < 4; ++r) {
                    const int h = hb + r;
                    const bool live = (h != c) && (mhv[mf][r] != 0.f) && (mcv[nf] != 0.f);
                    if (live) {
                        const float eng = S[mf][nf][r] + SDb[h] + sev + bk;
                        aacc[mf][nf][r] += __expf(eng);
                        if (c >= 1 && tgv[nf] == kk && hdv[nf] == h) { tacc += eng; hit = true; }
                    }
                }
            }
        }
    }

    // write tile slice (unique ownership, no atomics)
    float* Ab = A10 + ((size_t)((sliceBase + kg)*BB + b))*LL*LL;
#pragma unroll
    for (int mf = 0; mf < 2; ++mf) {
        const int hb = h0 + mf*16 + l4*4;
#pragma unroll
        for (int r = 0; r < 4; ++r)
#pragma unroll
            for (int nf = 0; nf < 2; ++nf)
                Ab[(hb + r)*LL + c0 + nf*16 + l15] = aacc[mf][nf][r];
    }
    if (hit) atomicAdd(&tgt[b], tacc);
}

// ---------------------------------------------------------------------------
// Register-resident LU logdet; sums the NSL A-slices during the As load.
// float4 L/U publish, double-buffered -> one barrier per pivot step.
// ---------------------------------------------------------------------------
__global__ __launch_bounds__(256) void k_logdet(
    const float* __restrict__ A10, const int* __restrict__ lengths,
    const float* __restrict__ tgt, float* __restrict__ out)
{
    const int b = blockIdx.x;
    const int t = threadIdx.x;
    const int rg = t >> 4, cg = t & 15;

    __shared__ float As[LL*LL];
    __shared__ float Dg[128];
    __shared__ float Lb[2][128];
    __shared__ float Ub[2][128];
    __shared__ float Pv[128];
    __shared__ float red[256];

    const float4* A4 = (const float4*)A10;
    for (int f4 = t; f4 < 4096; f4 += 256) {
        float4 x = make_float4(0.f, 0.f, 0.f, 0.f);
#pragma unroll
        for (int s = 0; s < NSL; ++s) {
            float4 y = A4[(size_t)(s*BB + b)*4096 + f4];
            x.x += y.x; x.y += y.y; x.z += y.z; x.w += y.w;
        }
        ((float4*)As)[f4] = x;
    }
    __syncthreads();

    if (t < 128) {
        float s = 0.f;
        for (int hr = 0; hr < LL; ++hr) s += As[hr*LL + t];
        Dg[t] = s * (1.0f + 1e-4f) + 1e-6f;
    }
    __syncthreads();

    const int n1 = lengths[b] - 1;
    float m[8][8];
#pragma unroll
    for (int r = 0; r < 8; ++r) {
        const int i = 8*rg + r;
#pragma unroll
        for (int c = 0; c < 8; ++c) {
            const int j = 8*cg + c;
            float v;
            if (i < n1 && j < n1)
                v = ((i == j) ? Dg[i+1] : 0.f) - As[(i+1)*LL + (j+1)];
            else
                v = (i == j) ? 1.f : 0.f;
            m[r][c] = v;
        }
    }
    // publish pivot 0
    if (cg == 0) {
        *(float4*)&Lb[0][8*rg]     = make_float4(m[0][0], m[1][0], m[2][0], m[3][0]);
        *(float4*)&Lb[0][8*rg + 4] = make_float4(m[4][0], m[5][0], m[6][0], m[7][0]);
    }
    if (rg == 0) {
        *(float4*)&Ub[0][8*cg]     = make_float4(m[0][0], m[0][1], m[0][2], m[0][3]);
        *(float4*)&Ub[0][8*cg + 4] = make_float4(m[0][4], m[0][5], m[0][6], m[0][7]);
    }
    __syncthreads();

    for (int j = 0; j < 127; ++j) {
        const int cur = j & 1, nxt = cur ^ 1;
        const float piv = Lb[cur][j];
        if (t == j) Pv[j] = piv;
        const float rp = 1.0f / piv;
        const float4 l0 = *(const float4*)&Lb[cur][8*rg];
        const float4 l1 = *(const float4*)&Lb[cur][8*rg + 4];
        const float4 u0 = *(const float4*)&Ub[cur][8*cg];
        const float4 u1 = *(const float4*)&Ub[cur][8*cg + 4];
        const float lr[8] = { l0.x*rp, l0.y*rp, l0.z*rp, l0.w*rp,
                              l1.x*rp, l1.y*rp, l1.z*rp, l1.w*rp };
        const float ur[8] = { u0.x, u0.y, u0.z, u0.w, u1.x, u1.y, u1.z, u1.w };
#pragma unroll
        for (int r = 0; r < 8; ++r)
#pragma unroll
            for (int c = 0; c < 8; ++c)
                m[r][c] = fmaf(-lr[r], ur[c], m[r][c]);

        if (j < 126) {
            const int jn = j + 1, jg = jn >> 3, jl = jn & 7;
            if (cg == jg) {
#pragma unroll
                for (int c = 0; c < 8; ++c) {
                    if (c == jl) {
                        *(float4*)&Lb[nxt][8*rg]     = make_float4(m[0][c], m[1][c], m[2][c], m[3][c]);
                        *(float4*)&Lb[nxt][8*rg + 4] = make_float4(m[4][c], m[5][c], m[6][c], m[7][c]);
                    }
                }
            }
            if (rg == jg) {
#pragma unroll
                for (int r = 0; r < 8; ++r) {
                    if (r == jl) {
                        *(float4*)&Ub[nxt][8*cg]     = make_float4(m[r][0], m[r][1], m[r][2], m[r][3]);
                        *(float4*)&Ub[nxt][8*cg + 4] = make_float4(m[r][4], m[r][5], m[r][6], m[r][7]);
                    }
                }
            }
        }
        __syncthreads();
    }

    float lsum = 0.f;
    if (t < 127) lsum = logf(Pv[t]);
    red[t] = lsum;
    __syncthreads();
    for (int off = 128; off >= 1; off >>= 1) {
        if (t < off) red[t] += red[t + off];
        __syncthreads();
    }
    if (t == 0) out[b] = red[0] - tgt[b];
}

// ---------------------------------------------------------------------------
extern "C" void kernel_launch(void* const* d_in, const int* in_sizes, int n_in,
                              void* d_out, int out_size, void* d_ws, size_t ws_size,
                              hipStream_t stream) {
    const float* H    = (const float*)d_in[0];
    const float* C    = (const float*)d_in[1];
    const float* Wd   = (const float*)d_in[2];
    const float* We   = (const float*)d_in[3];
    const float* U    = (const float*)d_in[4];
    const float* bv   = (const float*)d_in[5];
    const float* mask = (const float*)d_in[6];
    const int* heads  = (const int*)d_in[7];
    const int* tags   = (const int*)d_in[8];
    const int* lens   = (const int*)d_in[9];
    float* out = (float*)d_out;

    // workspace layout (~114 MB)
    char* p = (char*)d_ws;
    float* tgt = (float*)p;                 p += 128*4;
    float* A10 = (float*)p;                 p += (size_t)NSL*BB*LL*LL*4;    // 20.97 MB
    float* SDp = (float*)p;                 p += (size_t)BB*KK*LL*4;        // 0.66 MB
    float* SEp = (float*)p;                 p += (size_t)BB*KK*LL*4;        // 0.66 MB
    short* Hsp = (short*)p;                 p += (size_t)BB*SDN*LL*8*2;     // 3.41 MB
    short* Csp = (short*)p;                 p += (size_t)BB*SEN*LL*8*2;     // 3.41 MB
    short* Usp = (short*)p;                 p += (size_t)KK*SDN*EP*8*2;     // 17.04 MB
    short* Tbp = (short*)p;                 p += (size_t)KHALF*BB*SEN*LL*8*2; // 68.16 MB

    hipMemsetAsync(tgt, 0, 128*4, stream);

    p_hc  <<<dim3(1664), 256, 0, stream>>>(H, C, Hsp, Csp);
    p_u   <<<dim3(4160), 256, 0, stream>>>(U, Usp);
    k_sdse<<<dim3(BB*KK), 256, 0, stream>>>(H, C, Wd, We, SDp, SEp);

    for (int half = 0; half < 2; ++half) {
        const int k0 = half * KHALF;
        k_T<<<dim3(4, BB, KHALF), 256, 0, stream>>>(Usp, Hsp, Tbp, k0);
        k_A<<<dim3(4, BB, NG), 256, 0, stream>>>(Tbp, Csp, SDp, SEp, bv, mask,
                                                 heads, tags, A10, tgt, k0, half*NG);
    }

    k_logdet<<<dim3(BB), 256, 0, stream>>>(A10, lens, tgt, out);
}